// Round 9
// baseline (292.131 us; speedup 1.0000x reference)
//
#include <hip/hip_runtime.h>
#include <cmath>

// ---------------------------------------------------------------------------
// Bit-exact replication of the reference's f32 cumsum TREE (JAX associative
// scan), validated rounds 5-8 (absmax 1.831e-3 all). Round 8 post-mortem:
// VGPR_Count=48 == acc[16]+temps -> the allocator SPILLED the loop-invariant
// arrays (u/w/ao) chasing 10-waves/SIMD occupancy the 768-block grid can't
// use; ~700 MB of scratch reloads hit L2 (FETCH only 13 MB => L2-resident)
// making the k-loop L2-latency-bound (VALUBusy 22%, all pipes idle).
// __launch_bounds__'s 2nd arg only caps VGPRs (min waves); it does not lower
// the allocator's occupancy TARGET. Fix: amdgpu_waves_per_eu(2,4) pins the
// target at 4 waves/EU -> 128-VGPR budget actually used -> no spills.
// Arithmetic dag unchanged.
// ---------------------------------------------------------------------------
#pragma clang fp contract(off)

#define SRF   48000.0f
#define NYQF  21600.0f                    // fp32(48000*0.45), exact
constexpr float  TWO_PI_F  = 6.283185307179586476925286766559f;  // 0x40C90FDB
constexpr double INV_2PI_D = 0.15915494309189533576888376337251;
constexpr float  RC1 = (float)INV_2PI_D;
constexpr float  RC2 = (float)(INV_2PI_D - (double)RC1);
constexpr double INV_SR_D = 1.0 / 48000.0;
constexpr float  DD1 = (float)INV_SR_D;
constexpr float  DD2 = (float)(INV_SR_D - (double)DD1);

__device__ __forceinline__ float hsin_rev(float r) {  // sin(2*pi*r)
#if __has_builtin(__builtin_amdgcn_sinf)
    return __builtin_amdgcn_sinf(r);                  // v_sin_f32: revolutions
#else
    return __sinf(r * TWO_PI_F);
#endif
}

// Correctly-rounded t/48000 via double-float mul (== IEEE f32 divide here;
// proved: no halfway cases, err 2^-47 << 2^-33.5 boundary distance).
__device__ __forceinline__ float div48000(float t) {
    float h = t * DD1;
    float r = __builtin_fmaf(t, DD1, -h);
    float s = __builtin_fmaf(t, DD2, r);
    return h + s;
}

// sin(ph) for f32 ph: double-float reduction to revolutions (|err|<=2^-25 rev)
__device__ __forceinline__ float sin_phase(float ph) {
    float h  = ph * RC1;
    float r  = __builtin_fmaf(ph, RC1, -h);
    float s  = __builtin_fmaf(ph, RC2, r);
    float nn = __builtin_rintf(h);
    float fr = (h - nn) + s;
    return hsin_rev(fr);
}

// kc[b,k] = fp32(k * fp32(sqrt(fp32(1 + fp32(inh*k^2)))))  -- np/jnp-exact
__device__ __forceinline__ float kcval(int k, float ib) {
    float kf = (float)(k + 1);
    float k2 = kf * kf;
    float m  = ib * k2;
    float s1 = 1.0f + m;
    float st = (float)sqrt((double)s1);
    return kf * st;
}

// ---- K1: f0_up[b,j], np-exact fp32 linear interp ---------------------------
__global__ void __launch_bounds__(256) k_f0up(const float* __restrict__ f0,
        float* __restrict__ f0up, int T, int n, float pf) {
    int j = blockIdx.x * 256 + threadIdx.x;
    int b = blockIdx.y;
    if (j >= n) return;
    float pos = ((float)j + 0.5f);
    pos = pos * pf;
    pos = pos - 0.5f;
    pos = fmaxf(pos, 0.0f);
    pos = fminf(pos, (float)(T - 1));
    int   i0 = (int)pos;
    int   i1 = min(i0 + 1, T - 1);
    float w  = pos - (float)i0;
    float omw = 1.0f - w;
    const float* fb = f0 + b * T;
    f0up[(size_t)b * n + j] = fb[i0] * omw + fb[i1] * w;
}

// ---- K2a: per (b,k) produce scan4 (level-4 inclusive tree scan) ------------
__global__ void __launch_bounds__(256)
__attribute__((amdgpu_waves_per_eu(2, 4)))
k_scan4(const float* __restrict__ f0up,
        const float* __restrict__ inh, float* __restrict__ scan4,
        int N, int n) {
    __shared__ float lv[6016];
    const int k   = blockIdx.x;
    const int b   = blockIdx.y;
    const int tid = threadIdx.x;
    const float kc = kcval(k, inh[b]);
    const float4* f4 = (const float4*)(f0up + (size_t)b * n);
    const int len4 = n >> 4;

    // L4 from increments, prefetched one chunk ahead
    {
        int i = tid;
        float4 c0 = {}, c1 = {}, c2 = {}, c3 = {};
        if (i < len4) { c0 = f4[4*i]; c1 = f4[4*i+1]; c2 = f4[4*i+2]; c3 = f4[4*i+3]; }
        while (i < len4) {
            int ni = i + 256;
            float4 n0 = {}, n1 = {}, n2 = {}, n3 = {};
            if (ni < len4) { n0 = f4[4*ni]; n1 = f4[4*ni+1]; n2 = f4[4*ni+2]; n3 = f4[4*ni+3]; }
            float a0=div48000(TWO_PI_F*(kc*c0.x)), a1=div48000(TWO_PI_F*(kc*c0.y));
            float a2=div48000(TWO_PI_F*(kc*c0.z)), a3=div48000(TWO_PI_F*(kc*c0.w));
            float a4=div48000(TWO_PI_F*(kc*c1.x)), a5=div48000(TWO_PI_F*(kc*c1.y));
            float a6=div48000(TWO_PI_F*(kc*c1.z)), a7=div48000(TWO_PI_F*(kc*c1.w));
            float a8=div48000(TWO_PI_F*(kc*c2.x)), a9=div48000(TWO_PI_F*(kc*c2.y));
            float aA=div48000(TWO_PI_F*(kc*c2.z)), aB=div48000(TWO_PI_F*(kc*c2.w));
            float aC=div48000(TWO_PI_F*(kc*c3.x)), aD=div48000(TWO_PI_F*(kc*c3.y));
            float aE=div48000(TWO_PI_F*(kc*c3.z)), aF=div48000(TWO_PI_F*(kc*c3.w));
            float L2a=(a0+a1)+(a2+a3), L2b=(a4+a5)+(a6+a7);
            float L2c=(a8+a9)+(aA+aB), L2d=(aC+aD)+(aE+aF);
            lv[i] = (L2a+L2b) + (L2c+L2d);
            i = ni; c0 = n0; c1 = n1; c2 = n2; c3 = n3;
        }
    }
    __syncthreads();

    // upsweep
    int offp = 0, lenp = len4, P = 4;
    for (int l = 5; ; ++l) {
        int lenc = lenp >> 1;
        int offc = offp + lenp;
        for (int i = tid; i < lenc; i += 256)
            lv[offc + i] = lv[offp + 2*i] + lv[offp + 2*i + 1];
        __syncthreads();
        P = l;
        if (lenc == 1) break;
        offp = offc; lenp = lenc;
    }
    // downsweep (round-5-validated formulas)
    for (int l = P - 1; l >= 4; --l) {
        int lenl = n >> l;
        int offl = 0;
        for (int m = 4; m < l; ++m) offl += (n >> m);
        int offh = offl + lenl;
        int lenh = n >> (l + 1);
        float*       arr = lv + offl;
        const float* hi  = lv + offh;
        for (int i = tid; i < lenh; i += 256) {
            float v = hi[i];
            int e = 2*i + 2;
            if (e < lenl) arr[e] = v + arr[e];
            arr[2*i + 1] = v;
        }
        __syncthreads();
    }
    float* sp = scan4 + (size_t)(b * N + k) * len4;
    for (int i = tid; i < len4; i += 256) sp[i] = lv[i];
}

// ---- K2b: 16 consecutive j per thread, uniform reconstruction from scan4 ---
#define ROWS 26
__global__ void __launch_bounds__(256)
__attribute__((amdgpu_waves_per_eu(2, 4)))
k_synth3(
        const float* __restrict__ harm, const float* __restrict__ f0up,
        const float* __restrict__ inh,  const float* __restrict__ scan4,
        float* __restrict__ out, int B, int T, int N, int n, float pf, int kpg) {
    const int tid  = threadIdx.x;
    const int b    = blockIdx.y;
    const int k0   = blockIdx.z * kpg;
    const int q    = blockIdx.x * 256 + tid;      // 16-sample group id
    const int NG   = n >> 4;
    const int kend = min(k0 + kpg, N);
    const int kact = kend - k0;

    __shared__ float2 amps[ROWS * 32];            // (row r, row r+1) x k
    __shared__ float  kcs[32];

    const float ib    = inh[b];
    const float tmaxf = (float)(T - 1);

    for (int i = tid; i < kact; i += 256) kcs[i] = kcval(k0 + i, ib);

    const int j0blk = blockIdx.x * 4096;
    int i0min;
    {
        float p = ((float)j0blk + 0.5f);
        p = p * pf; p = p - 0.5f;
        p = fmaxf(p, 0.0f); p = fminf(p, tmaxf);
        i0min = (int)p;
    }
    for (int idx = tid; idx < ROWS * kact; idx += 256) {
        int r = idx / kact, kk = idx - r * kact;
        int r0 = min(i0min + r, T - 1);
        int r1 = min(i0min + r + 1, T - 1);
        amps[idx] = make_float2(harm[((size_t)b * T + r0) * N + (k0 + kk)],
                                harm[((size_t)b * T + r1) * N + (k0 + kk)]);
    }
    __syncthreads();                              // last barrier

    float u[16], w[16];
    int   ao[16];
    float um = __builtin_inff();
    if (q < NG) {
        const float4* up = (const float4*)(f0up + (size_t)b * n + (size_t)q * 16);
        float4 v0 = up[0], v1 = up[1], v2 = up[2], v3 = up[3];
        u[0]=v0.x; u[1]=v0.y; u[2]=v0.z; u[3]=v0.w;
        u[4]=v1.x; u[5]=v1.y; u[6]=v1.z; u[7]=v1.w;
        u[8]=v2.x; u[9]=v2.y; u[10]=v2.z; u[11]=v2.w;
        u[12]=v3.x; u[13]=v3.y; u[14]=v3.z; u[15]=v3.w;
        #pragma unroll
        for (int i = 0; i < 16; ++i) {
            um = fminf(um, u[i]);
            int j = q * 16 + i;
            float p = ((float)j + 0.5f);
            p = p * pf; p = p - 0.5f;
            p = fmaxf(p, 0.0f); p = fminf(p, tmaxf);
            int i0 = (int)p;
            w[i]  = p - (float)i0;
            ao[i] = (i0 - i0min) * kact;
        }
    }
    // per-wave min (finer early-exit than block min; no barriers)
    #pragma unroll
    for (int off = 32; off > 0; off >>= 1)
        um = fminf(um, __shfl_xor(um, off));
    const float umin = um;

    if (q < NG) {
        float acc[16];
        #pragma unroll
        for (int i = 0; i < 16; ++i) acc[i] = 0.0f;

        const float* s4k = scan4 + (size_t)(b * N + k0) * NG;
        float g0c = (q == 0) ? 0.0f : s4k[q - 1];
        float g1c = s4k[q];

        for (int k = k0; k < kend; ++k) {
            const int   kk = k - k0;
            const float kc = kcs[kk];
            if (kc * umin >= NYQF) break;         // wave-uniform; kc monotone
            const float g0 = g0c, g1 = g1c;
            if (k + 1 < kend) {                   // prefetch next k row
                const float* nx = s4k + NG;
                g0c = (q == 0) ? 0.0f : nx[q - 1];
                g1c = nx[q];
                s4k = nx;
            }

            float x[16];
            #pragma unroll
            for (int i = 0; i < 16; ++i)
                x[i] = div48000(TWO_PI_F * (kc * u[i]));

            // tree partials (round-5-validated associations)
            float L1a = x[0]+x[1],   L1b = x[2]+x[3];
            float L1c = x[4]+x[5],   L1d = x[6]+x[7];
            float L1e = x[8]+x[9],   L1f = x[10]+x[11];
            float L1g = x[12]+x[13];
            float L2a = L1a+L1b, L2b = L1c+L1d, L2c = L1e+L1f;
            float L3a = L2a+L2b;
            float p0  = g0 + x[0];
            float s10 = g0 + L1a;
            float p2  = s10 + x[2];
            float s20 = g0 + L2a;
            float p4  = s20 + x[4];
            float s12 = s20 + L1c;
            float p6  = s12 + x[6];
            float s3v = g0 + L3a;
            float p8  = s3v + x[8];
            float s14 = s3v + L1e;
            float p10 = s14 + x[10];
            float s22 = s3v + L2c;
            float p12 = s22 + x[12];
            float s16 = s22 + L1g;
            float p14 = s16 + x[14];

            auto emit = [&](int i, float ph) {
                float t1 = kc * u[i];             // same RN product as ref mask
                if (t1 < NYQF) {
                    float  sv  = sin_phase(ph);
                    float2 a01 = amps[ao[i] + kk];
                    float  wv  = w[i];
                    float  a   = a01.x * (1.0f - wv) + a01.y * wv;
                    acc[i] += a * sv;
                }
            };
            emit(0, p0);   emit(1, s10);  emit(2, p2);   emit(3, s20);
            emit(4, p4);   emit(5, s12);  emit(6, p6);   emit(7, s3v);
            emit(8, p8);   emit(9, s14);  emit(10, p10); emit(11, s22);
            emit(12, p12); emit(13, s16); emit(14, p14); emit(15, g1);
        }

        const float Nf = (float)N;
        float* ob = out + (size_t)b * n + (size_t)q * 16;
        #pragma unroll
        for (int i = 0; i < 16; ++i) atomicAdd(&ob[i], acc[i] / Nf);
    }
}

// ---- Fallback: round-5 proven kernel (atomics, 96 KB LDS) ------------------
__global__ void __launch_bounds__(256) k_scan_synth(
        const float* __restrict__ harm, const float* __restrict__ f0up,
        const float* __restrict__ inh,  float* __restrict__ out,
        int B, int T, int N, int n, float pf) {
    extern __shared__ float lv[];
    const int k   = blockIdx.x;
    const int b   = blockIdx.y;
    const int tid = threadIdx.x;
    const float kc = kcval(k, inh[b]);
    const float* fb = f0up + (size_t)b * n;

    auto inc = [&](int j) -> float {
        float u    = fb[j];
        float inst = kc * u;
        float tt   = TWO_PI_F * inst;
        return tt / SRF;
    };

    const int len1 = n >> 1;
    {
        const float4* f4 = (const float4*)fb;
        for (int i = tid; i < (n >> 2); i += 256) {
            float4 u = f4[i];
            float a0 = (TWO_PI_F * (kc * u.x)) / SRF;
            float a1 = (TWO_PI_F * (kc * u.y)) / SRF;
            float a2 = (TWO_PI_F * (kc * u.z)) / SRF;
            float a3 = (TWO_PI_F * (kc * u.w)) / SRF;
            lv[i] = (a0 + a1) + (a2 + a3);
        }
    }
    __syncthreads();
    int offp = 0, lenp = n >> 2, P = 2;
    for (int l = 3; ; ++l) {
        int lenc = lenp >> 1;
        int offc = offp + lenp;
        for (int i = tid; i < lenc; i += 256)
            lv[offc + i] = lv[offp + 2*i] + lv[offp + 2*i + 1];
        __syncthreads();
        P = l;
        if (lenc == 1) break;
        offp = offc; lenp = lenc;
    }
    for (int l = P - 1; l >= 2; --l) {
        int lenl = n >> l;
        int offl = 0;
        for (int m = 2; m < l; ++m) offl += (n >> m);
        float*       arr = lv + offl;
        const float* hi  = lv + offl + lenl;
        int lenh = n >> (l + 1);
        for (int i = tid; i < lenh; i += 256) {
            float v = hi[i];
            int e = 2*i + 2;
            if (e < lenl) arr[e] = v + arr[e];
            arr[2*i + 1] = v;
        }
        __syncthreads();
    }
    const float* scan2 = lv;

    const float  tmaxf = (float)(T - 1);
    const float  invN  = 1.0f / (float)N;
    const float* hb    = harm + (size_t)b * T * N + k;
    float*       ob    = out + (size_t)b * n;

    auto emit = [&](int j, float ph) {
        float u    = fb[j];
        float inst = kc * u;
        if (!(inst < NYQF)) return;
        double pr = (double)ph * INV_2PI_D;
        double fr = pr - rint(pr);
        float  sv = hsin_rev((float)fr);
        float pos = ((float)j + 0.5f);
        pos = pos * pf; pos = pos - 0.5f;
        pos = fmaxf(pos, 0.0f); pos = fminf(pos, tmaxf);
        int   i0 = (int)pos;
        int   i1 = min(i0 + 1, T - 1);
        float w  = pos - (float)i0;
        float a  = hb[(size_t)i0 * N] * (1.0f - w) + hb[(size_t)i1 * N] * w;
        atomicAdd(&ob[j], (a * sv) * invN);
    };

    if (tid == 0) emit(0, inc(0));
    for (int tt = tid; tt < len1; tt += 256) {
        float s1;
        if (tt == 0)      s1 = inc(0) + inc(1);
        else if (tt & 1)  s1 = scan2[(tt - 1) >> 1];
        else              s1 = scan2[(tt >> 1) - 1] + (inc(2*tt) + inc(2*tt + 1));
        emit(2*tt + 1, s1);
        int je = 2*tt + 2;
        if (je < n) emit(je, s1 + inc(je));
    }
}

extern "C" void kernel_launch(void* const* d_in, const int* in_sizes, int n_in,
                              void* d_out, int out_size, void* d_ws, size_t ws_size,
                              hipStream_t stream) {
    const int B = in_sizes[2];                 // 16
    const int T = in_sizes[1] / B;             // 250
    const int N = in_sizes[0] / (B * T);       // 100
    const int n = out_size / B;                // 48000
    const float pf = (float)((double)T / (double)n);

    const float* harm = (const float*)d_in[0];
    const float* f0   = (const float*)d_in[1];
    const float* inh  = (const float*)d_in[2];
    float* out  = (float*)d_out;
    float* f0up = (float*)d_ws;                // B*n floats = 3.07 MB

    const int KZ  = 4;
    const int kpg = (N + KZ - 1) / KZ;         // 25
    const size_t needFast = (size_t)B * n * 4 + (size_t)B * N * (n / 16) * 4;
    const bool fast = (ws_size >= needFast) && (n % 16 == 0) && (kpg <= 32);

    k_f0up<<<dim3((n + 255) / 256, B), 256, 0, stream>>>(f0, f0up, T, n, pf);
    hipMemsetAsync(d_out, 0, (size_t)out_size * sizeof(float), stream);

    if (fast) {
        float* scan4 = (float*)((char*)d_ws + (size_t)B * n * 4);
        k_scan4<<<dim3(N, B), 256, 0, stream>>>(f0up, inh, scan4, N, n);
        const int NG    = n / 16;                          // 3000
        const int tiles = (NG + 255) / 256;                // 12
        k_synth3<<<dim3(tiles, B, KZ), 256, 0, stream>>>(
            harm, f0up, inh, scan4, out, B, T, N, n, pf, kpg);
    } else {
        const size_t lds_bytes = (size_t)(n / 2) * sizeof(float);  // 96 KB
        k_scan_synth<<<dim3(N, B), 256, lds_bytes, stream>>>(
            harm, f0up, inh, out, B, T, N, n, pf);
    }
}

// Round 10
// 159.390 us; speedup vs baseline: 1.8328x; 1.8328x over previous
//
#include <hip/hip_runtime.h>
#include <cmath>

// ---------------------------------------------------------------------------
// Bit-exact replication of the reference's f32 cumsum TREE (JAX associative
// scan), validated rounds 5-9 (absmax 1.831e-3 all). Rounds 7-9 showed the
// 16-j-per-thread shape loses to the register allocator (VGPR stuck ~50,
// arrays reloaded via L1/L2 every iter, VALUBusy 22%). Round 6 (occupancy
// 50%) ran faster with 3x worse code. Fix: k_synth4 splits each 16-j group
// across 4 lanes -> ~16 live values/lane (no allocator fight), 4x threads
// (47 waves/CU demand), tree partials combined with 3 intra-group shuffles
// (FP add commutative bitwise -> associations preserved exactly).
// ---------------------------------------------------------------------------
#pragma clang fp contract(off)

#define SRF   48000.0f
#define NYQF  21600.0f                    // fp32(48000*0.45), exact
constexpr float  TWO_PI_F  = 6.283185307179586476925286766559f;  // 0x40C90FDB
constexpr double INV_2PI_D = 0.15915494309189533576888376337251;
constexpr float  RC1 = (float)INV_2PI_D;
constexpr float  RC2 = (float)(INV_2PI_D - (double)RC1);
constexpr double INV_SR_D = 1.0 / 48000.0;
constexpr float  DD1 = (float)INV_SR_D;
constexpr float  DD2 = (float)(INV_SR_D - (double)DD1);

__device__ __forceinline__ float hsin_rev(float r) {  // sin(2*pi*r)
#if __has_builtin(__builtin_amdgcn_sinf)
    return __builtin_amdgcn_sinf(r);                  // v_sin_f32: revolutions
#else
    return __sinf(r * TWO_PI_F);
#endif
}

// Correctly-rounded t/48000 via double-float mul (== IEEE f32 divide here;
// proved: no halfway cases, err 2^-47 << 2^-33.5 boundary distance).
__device__ __forceinline__ float div48000(float t) {
    float h = t * DD1;
    float r = __builtin_fmaf(t, DD1, -h);
    float s = __builtin_fmaf(t, DD2, r);
    return h + s;
}

// sin(ph) for f32 ph: double-float reduction to revolutions (|err|<=2^-25 rev)
__device__ __forceinline__ float sin_phase(float ph) {
    float h  = ph * RC1;
    float r  = __builtin_fmaf(ph, RC1, -h);
    float s  = __builtin_fmaf(ph, RC2, r);
    float nn = __builtin_rintf(h);
    float fr = (h - nn) + s;
    return hsin_rev(fr);
}

// kc[b,k] = fp32(k * fp32(sqrt(fp32(1 + fp32(inh*k^2)))))  -- np/jnp-exact
__device__ __forceinline__ float kcval(int k, float ib) {
    float kf = (float)(k + 1);
    float k2 = kf * kf;
    float m  = ib * k2;
    float s1 = 1.0f + m;
    float st = (float)sqrt((double)s1);
    return kf * st;
}

// ---- K1: f0_up[b,j], np-exact fp32 linear interp ---------------------------
__global__ void __launch_bounds__(256) k_f0up(const float* __restrict__ f0,
        float* __restrict__ f0up, int T, int n, float pf) {
    int j = blockIdx.x * 256 + threadIdx.x;
    int b = blockIdx.y;
    if (j >= n) return;
    float pos = ((float)j + 0.5f);
    pos = pos * pf;
    pos = pos - 0.5f;
    pos = fmaxf(pos, 0.0f);
    pos = fminf(pos, (float)(T - 1));
    int   i0 = (int)pos;
    int   i1 = min(i0 + 1, T - 1);
    float w  = pos - (float)i0;
    float omw = 1.0f - w;
    const float* fb = f0 + b * T;
    f0up[(size_t)b * n + j] = fb[i0] * omw + fb[i1] * w;
}

// ---- K2a: per (b,k) produce scan4 (level-4 inclusive tree scan) ------------
__global__ void __launch_bounds__(256) k_scan4(const float* __restrict__ f0up,
        const float* __restrict__ inh, float* __restrict__ scan4,
        int N, int n) {
    __shared__ float lv[6016];
    const int k   = blockIdx.x;
    const int b   = blockIdx.y;
    const int tid = threadIdx.x;
    const float kc = kcval(k, inh[b]);
    const float4* f4 = (const float4*)(f0up + (size_t)b * n);
    const int len4 = n >> 4;

    // L4 from increments, prefetched one chunk ahead
    {
        int i = tid;
        float4 c0 = {}, c1 = {}, c2 = {}, c3 = {};
        if (i < len4) { c0 = f4[4*i]; c1 = f4[4*i+1]; c2 = f4[4*i+2]; c3 = f4[4*i+3]; }
        while (i < len4) {
            int ni = i + 256;
            float4 n0 = {}, n1 = {}, n2 = {}, n3 = {};
            if (ni < len4) { n0 = f4[4*ni]; n1 = f4[4*ni+1]; n2 = f4[4*ni+2]; n3 = f4[4*ni+3]; }
            float a0=div48000(TWO_PI_F*(kc*c0.x)), a1=div48000(TWO_PI_F*(kc*c0.y));
            float a2=div48000(TWO_PI_F*(kc*c0.z)), a3=div48000(TWO_PI_F*(kc*c0.w));
            float a4=div48000(TWO_PI_F*(kc*c1.x)), a5=div48000(TWO_PI_F*(kc*c1.y));
            float a6=div48000(TWO_PI_F*(kc*c1.z)), a7=div48000(TWO_PI_F*(kc*c1.w));
            float a8=div48000(TWO_PI_F*(kc*c2.x)), a9=div48000(TWO_PI_F*(kc*c2.y));
            float aA=div48000(TWO_PI_F*(kc*c2.z)), aB=div48000(TWO_PI_F*(kc*c2.w));
            float aC=div48000(TWO_PI_F*(kc*c3.x)), aD=div48000(TWO_PI_F*(kc*c3.y));
            float aE=div48000(TWO_PI_F*(kc*c3.z)), aF=div48000(TWO_PI_F*(kc*c3.w));
            float L2a=(a0+a1)+(a2+a3), L2b=(a4+a5)+(a6+a7);
            float L2c=(a8+a9)+(aA+aB), L2d=(aC+aD)+(aE+aF);
            lv[i] = (L2a+L2b) + (L2c+L2d);
            i = ni; c0 = n0; c1 = n1; c2 = n2; c3 = n3;
        }
    }
    __syncthreads();

    // upsweep
    int offp = 0, lenp = len4, P = 4;
    for (int l = 5; ; ++l) {
        int lenc = lenp >> 1;
        int offc = offp + lenp;
        for (int i = tid; i < lenc; i += 256)
            lv[offc + i] = lv[offp + 2*i] + lv[offp + 2*i + 1];
        __syncthreads();
        P = l;
        if (lenc == 1) break;
        offp = offc; lenp = lenc;
    }
    // downsweep (round-5-validated formulas)
    for (int l = P - 1; l >= 4; --l) {
        int lenl = n >> l;
        int offl = 0;
        for (int m = 4; m < l; ++m) offl += (n >> m);
        int offh = offl + lenl;
        int lenh = n >> (l + 1);
        float*       arr = lv + offl;
        const float* hi  = lv + offh;
        for (int i = tid; i < lenh; i += 256) {
            float v = hi[i];
            int e = 2*i + 2;
            if (e < lenl) arr[e] = v + arr[e];
            arr[2*i + 1] = v;
        }
        __syncthreads();
    }
    float* sp = scan4 + (size_t)(b * N + k) * len4;
    for (int i = tid; i < len4; i += 256) sp[i] = lv[i];
}

// ---- K2b: 4 lanes per 16-j group; tree partials via intra-group shuffles ---
__global__ void __launch_bounds__(256) k_synth4(
        const float* __restrict__ harm, const float* __restrict__ f0up,
        const float* __restrict__ inh,  const float* __restrict__ scan4,
        float* __restrict__ out, int B, int T, int N, int n, float pf, int kpg) {
    const int tid  = threadIdx.x;
    const int b    = blockIdx.y;
    const int k0   = blockIdx.z * kpg;
    const int g    = blockIdx.x * 256 + tid;   // global lane id
    const int q    = g >> 2;                   // 16-sample group
    const int c    = g & 3;                    // quarter within group
    const int NG   = n >> 4;
    const int kend = min(k0 + kpg, N);
    const int kact = kend - k0;
    const bool valid = q < NG;

    __shared__ float2 amps[8 * 32];            // 8 amp rows x k (block span 1024 j)
    __shared__ float  kcs[32];

    const float ib    = inh[b];
    const float tmaxf = (float)(T - 1);
    for (int i = tid; i < kact; i += 256) kcs[i] = kcval(k0 + i, ib);

    const int j0blk = blockIdx.x * 1024;
    int i0min;
    {
        float p = ((float)j0blk + 0.5f);
        p = p * pf; p = p - 0.5f;
        p = fmaxf(p, 0.0f); p = fminf(p, tmaxf);
        i0min = (int)p;
    }
    for (int idx = tid; idx < 8 * kact; idx += 256) {
        int r = idx / kact, kk = idx - r * kact;
        int r0 = min(i0min + r, T - 1);
        int r1 = min(i0min + r + 1, T - 1);
        amps[idx] = make_float2(harm[((size_t)b * T + r0) * N + (k0 + kk)],
                                harm[((size_t)b * T + r1) * N + (k0 + kk)]);
    }
    __syncthreads();                           // last barrier

    float u0=0.f,u1=0.f,u2=0.f,u3=0.f;
    float w0=0.f,w1=0.f,w2=0.f,w3=0.f;
    float o0=1.f,o1=1.f,o2=1.f,o3=1.f;         // 1-w (loop-invariant)
    int   a0o=0,a1o=0,a2o=0,a3o=0;
    float um = __builtin_inff();
    if (valid) {
        const float4 v = *(const float4*)(f0up + (size_t)b * n + (size_t)q * 16 + c * 4);
        u0=v.x; u1=v.y; u2=v.z; u3=v.w;
        um = fminf(fminf(u0,u1), fminf(u2,u3));
        const int jb = q * 16 + c * 4;
        #pragma unroll
        for (int i = 0; i < 4; ++i) {
            float p = ((float)(jb + i) + 0.5f);
            p = p * pf; p = p - 0.5f;
            p = fmaxf(p, 0.0f); p = fminf(p, tmaxf);
            int i0 = (int)p;
            float wv = p - (float)i0;
            int aoo  = (i0 - i0min) * kact;
            if (i==0){w0=wv;o0=1.0f-wv;a0o=aoo;}
            else if (i==1){w1=wv;o1=1.0f-wv;a1o=aoo;}
            else if (i==2){w2=wv;o2=1.0f-wv;a2o=aoo;}
            else {w3=wv;o3=1.0f-wv;a3o=aoo;}
        }
    }
    // wave-wide min for uniform early break
    #pragma unroll
    for (int off = 32; off > 0; off >>= 1)
        um = fminf(um, __shfl_xor(um, off));
    const float umin = um;
    const int lb = (tid & 63) & ~3;            // group base lane within wave

    if (valid) {
        float acc0=0.f, acc1=0.f, acc2=0.f, acc3=0.f;
        const float* s4k = scan4 + (size_t)(b * N + k0) * NG;
        float g0c = (q == 0) ? 0.0f : s4k[q - 1];
        float g1c = s4k[q];

        for (int k = k0; k < kend; ++k) {
            const int   kk = k - k0;
            const float kc = kcs[kk];
            if (kc * umin >= NYQF) break;      // wave-uniform; kc monotone in k
            const float G0 = g0c, G1 = g1c;
            if (k + 1 < kend) {                // prefetch next k row
                const float* nx = s4k + NG;
                g0c = (q == 0) ? 0.0f : nx[q - 1];
                g1c = nx[q];
                s4k = nx;
            }

            // lane-local increments (bit-exact vs ref elementwise ops)
            float x0 = div48000(TWO_PI_F * (kc * u0));
            float x1 = div48000(TWO_PI_F * (kc * u1));
            float x2 = div48000(TWO_PI_F * (kc * u2));
            float x3 = div48000(TWO_PI_F * (kc * u3));
            float L1p = x0 + x1, L1q = x2 + x3;
            float L2  = L1p + L1q;

            // group L2 partials (FP add commutative bitwise -> exact assoc)
            float s0 = __shfl(L2, lb);
            float s1 = __shfl(L2, lb + 1);
            float s2 = __shfl(L2, lb + 2);
            float t01 = s0 + s1;
            float b1v = G0 + s0;               // s20
            float b2v = G0 + t01;              // s3v  (g0 + (L2a+L2b))
            float b3v = b2v + s2;              // s22
            float base = (c == 0) ? G0  : (c == 1) ? b1v : (c == 2) ? b2v : b3v;
            float bn   = (c == 0) ? b1v : (c == 1) ? b2v : (c == 2) ? b3v : G1;

            float ph0 = base + x0;
            float ph1 = base + L1p;
            float ph2 = ph1 + x2;
            float ph3 = bn;

            {   float t1 = kc * u0;            // same RN product as ref mask
                if (t1 < NYQF) { float sv = sin_phase(ph0);
                    float2 a = amps[a0o + kk]; acc0 += (a.x*o0 + a.y*w0) * sv; } }
            {   float t1 = kc * u1;
                if (t1 < NYQF) { float sv = sin_phase(ph1);
                    float2 a = amps[a1o + kk]; acc1 += (a.x*o1 + a.y*w1) * sv; } }
            {   float t1 = kc * u2;
                if (t1 < NYQF) { float sv = sin_phase(ph2);
                    float2 a = amps[a2o + kk]; acc2 += (a.x*o2 + a.y*w2) * sv; } }
            {   float t1 = kc * u3;
                if (t1 < NYQF) { float sv = sin_phase(ph3);
                    float2 a = amps[a3o + kk]; acc3 += (a.x*o3 + a.y*w3) * sv; } }
        }

        const float Nf = (float)N;
        float* ob = out + (size_t)b * n + (size_t)q * 16 + c * 4;
        atomicAdd(&ob[0], acc0 / Nf);
        atomicAdd(&ob[1], acc1 / Nf);
        atomicAdd(&ob[2], acc2 / Nf);
        atomicAdd(&ob[3], acc3 / Nf);
    }
}

// ---- Fallback: round-5 proven kernel (atomics, 96 KB LDS) ------------------
__global__ void __launch_bounds__(256) k_scan_synth(
        const float* __restrict__ harm, const float* __restrict__ f0up,
        const float* __restrict__ inh,  float* __restrict__ out,
        int B, int T, int N, int n, float pf) {
    extern __shared__ float lv[];
    const int k   = blockIdx.x;
    const int b   = blockIdx.y;
    const int tid = threadIdx.x;
    const float kc = kcval(k, inh[b]);
    const float* fb = f0up + (size_t)b * n;

    auto inc = [&](int j) -> float {
        float u    = fb[j];
        float inst = kc * u;
        float tt   = TWO_PI_F * inst;
        return tt / SRF;
    };

    const int len1 = n >> 1;
    {
        const float4* f4 = (const float4*)fb;
        for (int i = tid; i < (n >> 2); i += 256) {
            float4 u = f4[i];
            float a0 = (TWO_PI_F * (kc * u.x)) / SRF;
            float a1 = (TWO_PI_F * (kc * u.y)) / SRF;
            float a2 = (TWO_PI_F * (kc * u.z)) / SRF;
            float a3 = (TWO_PI_F * (kc * u.w)) / SRF;
            lv[i] = (a0 + a1) + (a2 + a3);
        }
    }
    __syncthreads();
    int offp = 0, lenp = n >> 2, P = 2;
    for (int l = 3; ; ++l) {
        int lenc = lenp >> 1;
        int offc = offp + lenp;
        for (int i = tid; i < lenc; i += 256)
            lv[offc + i] = lv[offp + 2*i] + lv[offp + 2*i + 1];
        __syncthreads();
        P = l;
        if (lenc == 1) break;
        offp = offc; lenp = lenc;
    }
    for (int l = P - 1; l >= 2; --l) {
        int lenl = n >> l;
        int offl = 0;
        for (int m = 2; m < l; ++m) offl += (n >> m);
        float*       arr = lv + offl;
        const float* hi  = lv + offl + lenl;
        int lenh = n >> (l + 1);
        for (int i = tid; i < lenh; i += 256) {
            float v = hi[i];
            int e = 2*i + 2;
            if (e < lenl) arr[e] = v + arr[e];
            arr[2*i + 1] = v;
        }
        __syncthreads();
    }
    const float* scan2 = lv;

    const float  tmaxf = (float)(T - 1);
    const float  invN  = 1.0f / (float)N;
    const float* hb    = harm + (size_t)b * T * N + k;
    float*       ob    = out + (size_t)b * n;

    auto emit = [&](int j, float ph) {
        float u    = fb[j];
        float inst = kc * u;
        if (!(inst < NYQF)) return;
        double pr = (double)ph * INV_2PI_D;
        double fr = pr - rint(pr);
        float  sv = hsin_rev((float)fr);
        float pos = ((float)j + 0.5f);
        pos = pos * pf; pos = pos - 0.5f;
        pos = fmaxf(pos, 0.0f); pos = fminf(pos, tmaxf);
        int   i0 = (int)pos;
        int   i1 = min(i0 + 1, T - 1);
        float w  = pos - (float)i0;
        float a  = hb[(size_t)i0 * N] * (1.0f - w) + hb[(size_t)i1 * N] * w;
        atomicAdd(&ob[j], (a * sv) * invN);
    };

    if (tid == 0) emit(0, inc(0));
    for (int tt = tid; tt < len1; tt += 256) {
        float s1;
        if (tt == 0)      s1 = inc(0) + inc(1);
        else if (tt & 1)  s1 = scan2[(tt - 1) >> 1];
        else              s1 = scan2[(tt >> 1) - 1] + (inc(2*tt) + inc(2*tt + 1));
        emit(2*tt + 1, s1);
        int je = 2*tt + 2;
        if (je < n) emit(je, s1 + inc(je));
    }
}

extern "C" void kernel_launch(void* const* d_in, const int* in_sizes, int n_in,
                              void* d_out, int out_size, void* d_ws, size_t ws_size,
                              hipStream_t stream) {
    const int B = in_sizes[2];                 // 16
    const int T = in_sizes[1] / B;             // 250
    const int N = in_sizes[0] / (B * T);       // 100
    const int n = out_size / B;                // 48000
    const float pf = (float)((double)T / (double)n);

    const float* harm = (const float*)d_in[0];
    const float* f0   = (const float*)d_in[1];
    const float* inh  = (const float*)d_in[2];
    float* out  = (float*)d_out;
    float* f0up = (float*)d_ws;                // B*n floats = 3.07 MB

    const int KZ  = 4;
    const int kpg = (N + KZ - 1) / KZ;         // 25
    const size_t needFast = (size_t)B * n * 4 + (size_t)B * N * (n / 16) * 4;
    const bool fast = (ws_size >= needFast) && (n % 16 == 0) && (kpg <= 32);

    k_f0up<<<dim3((n + 255) / 256, B), 256, 0, stream>>>(f0, f0up, T, n, pf);
    hipMemsetAsync(d_out, 0, (size_t)out_size * sizeof(float), stream);

    if (fast) {
        float* scan4 = (float*)((char*)d_ws + (size_t)B * n * 4);
        k_scan4<<<dim3(N, B), 256, 0, stream>>>(f0up, inh, scan4, N, n);
        const int NG    = n / 16;                          // 3000
        const int tiles = (NG * 4 + 255) / 256;            // 47
        k_synth4<<<dim3(tiles, B, KZ), 256, 0, stream>>>(
            harm, f0up, inh, scan4, out, B, T, N, n, pf, kpg);
    } else {
        const size_t lds_bytes = (size_t)(n / 2) * sizeof(float);  // 96 KB
        k_scan_synth<<<dim3(N, B), 256, lds_bytes, stream>>>(
            harm, f0up, inh, out, B, T, N, n, pf);
    }
}

// Round 11
// 154.633 us; speedup vs baseline: 1.8892x; 1.0308x over previous
//
#include <hip/hip_runtime.h>
#include <cmath>

// ---------------------------------------------------------------------------
// Bit-exact replication of the reference's f32 cumsum TREE (JAX associative
// scan), validated rounds 5-10 (absmax 1.831e-3 all). Round 10 confirmed the
// occupancy/live-set theory: 4-lanes-per-16j synth -> VGPR 32, VALUBusy 77%,
// 64 us. Remaining: k_scan4 (~60 us vs ~10 us VALU floor) carries the same
// spill disease: its manual-prefetch phase-1 holds 8 float4s + 16 temps ~= 60
// live VGPRs against the default 64-VGPR (8-wave) budget. This round: slim
// phase-1 (one float4 at a time, ~12 live regs, exact same association), and
// fuse the out-zeroing into k_f0up (one fewer dispatch+gap). synth4 untouched.
// ---------------------------------------------------------------------------
#pragma clang fp contract(off)

#define SRF   48000.0f
#define NYQF  21600.0f                    // fp32(48000*0.45), exact
constexpr float  TWO_PI_F  = 6.283185307179586476925286766559f;  // 0x40C90FDB
constexpr double INV_2PI_D = 0.15915494309189533576888376337251;
constexpr float  RC1 = (float)INV_2PI_D;
constexpr float  RC2 = (float)(INV_2PI_D - (double)RC1);
constexpr double INV_SR_D = 1.0 / 48000.0;
constexpr float  DD1 = (float)INV_SR_D;
constexpr float  DD2 = (float)(INV_SR_D - (double)DD1);

__device__ __forceinline__ float hsin_rev(float r) {  // sin(2*pi*r)
#if __has_builtin(__builtin_amdgcn_sinf)
    return __builtin_amdgcn_sinf(r);                  // v_sin_f32: revolutions
#else
    return __sinf(r * TWO_PI_F);
#endif
}

// Correctly-rounded t/48000 via double-float mul (== IEEE f32 divide here;
// proved: no halfway cases, err 2^-47 << 2^-33.5 boundary distance).
__device__ __forceinline__ float div48000(float t) {
    float h = t * DD1;
    float r = __builtin_fmaf(t, DD1, -h);
    float s = __builtin_fmaf(t, DD2, r);
    return h + s;
}

// sin(ph) for f32 ph: double-float reduction to revolutions (|err|<=2^-25 rev)
__device__ __forceinline__ float sin_phase(float ph) {
    float h  = ph * RC1;
    float r  = __builtin_fmaf(ph, RC1, -h);
    float s  = __builtin_fmaf(ph, RC2, r);
    float nn = __builtin_rintf(h);
    float fr = (h - nn) + s;
    return hsin_rev(fr);
}

// kc[b,k] = fp32(k * fp32(sqrt(fp32(1 + fp32(inh*k^2)))))  -- np/jnp-exact
__device__ __forceinline__ float kcval(int k, float ib) {
    float kf = (float)(k + 1);
    float k2 = kf * kf;
    float m  = ib * k2;
    float s1 = 1.0f + m;
    float st = (float)sqrt((double)s1);
    return kf * st;
}

// ---- K1: f0_up[b,j] (np-exact fp32 interp) + zero-init of out --------------
__global__ void __launch_bounds__(256) k_f0up(const float* __restrict__ f0,
        float* __restrict__ f0up, float* __restrict__ out,
        int T, int n, float pf) {
    int j = blockIdx.x * 256 + threadIdx.x;
    int b = blockIdx.y;
    if (j >= n) return;
    float pos = ((float)j + 0.5f);
    pos = pos * pf;
    pos = pos - 0.5f;
    pos = fmaxf(pos, 0.0f);
    pos = fminf(pos, (float)(T - 1));
    int   i0 = (int)pos;
    int   i1 = min(i0 + 1, T - 1);
    float w  = pos - (float)i0;
    float omw = 1.0f - w;
    const float* fb = f0 + b * T;
    f0up[(size_t)b * n + j] = fb[i0] * omw + fb[i1] * w;
    out[(size_t)b * n + j]  = 0.0f;            // harness poisons out; we own it
}

// ---- K2a: per (b,k) produce scan4 (level-4 inclusive tree scan) ------------
// Slim phase-1: one float4 in flight, exact association (L2a+L2b)+(L2c+L2d).
__global__ void __launch_bounds__(256) k_scan4(const float* __restrict__ f0up,
        const float* __restrict__ inh, float* __restrict__ scan4,
        int N, int n) {
    __shared__ float lv[6016];
    const int k   = blockIdx.x;
    const int b   = blockIdx.y;
    const int tid = threadIdx.x;
    const float kc = kcval(k, inh[b]);
    const float4* f4 = (const float4*)(f0up + (size_t)b * n);
    const int len4 = n >> 4;

    auto l2of = [&](float4 v) -> float {
        float a0 = div48000(TWO_PI_F * (kc * v.x));
        float a1 = div48000(TWO_PI_F * (kc * v.y));
        float a2 = div48000(TWO_PI_F * (kc * v.z));
        float a3 = div48000(TWO_PI_F * (kc * v.w));
        return (a0 + a1) + (a2 + a3);
    };
    for (int i = tid; i < len4; i += 256) {
        float s01 = l2of(f4[4*i])     + l2of(f4[4*i + 1]);
        float s23 = l2of(f4[4*i + 2]) + l2of(f4[4*i + 3]);
        lv[i] = s01 + s23;                     // L4[i] = L3[2i]+L3[2i+1]
    }
    __syncthreads();

    // upsweep
    int offp = 0, lenp = len4, P = 4;
    for (int l = 5; ; ++l) {
        int lenc = lenp >> 1;
        int offc = offp + lenp;
        for (int i = tid; i < lenc; i += 256)
            lv[offc + i] = lv[offp + 2*i] + lv[offp + 2*i + 1];
        __syncthreads();
        P = l;
        if (lenc == 1) break;
        offp = offc; lenp = lenc;
    }
    // downsweep (round-5-validated formulas)
    for (int l = P - 1; l >= 4; --l) {
        int lenl = n >> l;
        int offl = 0;
        for (int m = 4; m < l; ++m) offl += (n >> m);
        int offh = offl + lenl;
        int lenh = n >> (l + 1);
        float*       arr = lv + offl;
        const float* hi  = lv + offh;
        for (int i = tid; i < lenh; i += 256) {
            float v = hi[i];
            int e = 2*i + 2;
            if (e < lenl) arr[e] = v + arr[e];
            arr[2*i + 1] = v;
        }
        __syncthreads();
    }
    float* sp = scan4 + (size_t)(b * N + k) * len4;
    for (int i = tid; i < len4; i += 256) sp[i] = lv[i];
}

// ---- K2b: 4 lanes per 16-j group; tree partials via intra-group shuffles ---
__global__ void __launch_bounds__(256) k_synth4(
        const float* __restrict__ harm, const float* __restrict__ f0up,
        const float* __restrict__ inh,  const float* __restrict__ scan4,
        float* __restrict__ out, int B, int T, int N, int n, float pf, int kpg) {
    const int tid  = threadIdx.x;
    const int b    = blockIdx.y;
    const int k0   = blockIdx.z * kpg;
    const int g    = blockIdx.x * 256 + tid;   // global lane id
    const int q    = g >> 2;                   // 16-sample group
    const int c    = g & 3;                    // quarter within group
    const int NG   = n >> 4;
    const int kend = min(k0 + kpg, N);
    const int kact = kend - k0;
    const bool valid = q < NG;

    __shared__ float2 amps[8 * 32];            // 8 amp rows x k (block span 1024 j)
    __shared__ float  kcs[32];

    const float ib    = inh[b];
    const float tmaxf = (float)(T - 1);
    for (int i = tid; i < kact; i += 256) kcs[i] = kcval(k0 + i, ib);

    const int j0blk = blockIdx.x * 1024;
    int i0min;
    {
        float p = ((float)j0blk + 0.5f);
        p = p * pf; p = p - 0.5f;
        p = fmaxf(p, 0.0f); p = fminf(p, tmaxf);
        i0min = (int)p;
    }
    for (int idx = tid; idx < 8 * kact; idx += 256) {
        int r = idx / kact, kk = idx - r * kact;
        int r0 = min(i0min + r, T - 1);
        int r1 = min(i0min + r + 1, T - 1);
        amps[idx] = make_float2(harm[((size_t)b * T + r0) * N + (k0 + kk)],
                                harm[((size_t)b * T + r1) * N + (k0 + kk)]);
    }
    __syncthreads();                           // last barrier

    float u0=0.f,u1=0.f,u2=0.f,u3=0.f;
    float w0=0.f,w1=0.f,w2=0.f,w3=0.f;
    float o0=1.f,o1=1.f,o2=1.f,o3=1.f;         // 1-w (loop-invariant)
    int   a0o=0,a1o=0,a2o=0,a3o=0;
    float um = __builtin_inff();
    if (valid) {
        const float4 v = *(const float4*)(f0up + (size_t)b * n + (size_t)q * 16 + c * 4);
        u0=v.x; u1=v.y; u2=v.z; u3=v.w;
        um = fminf(fminf(u0,u1), fminf(u2,u3));
        const int jb = q * 16 + c * 4;
        #pragma unroll
        for (int i = 0; i < 4; ++i) {
            float p = ((float)(jb + i) + 0.5f);
            p = p * pf; p = p - 0.5f;
            p = fmaxf(p, 0.0f); p = fminf(p, tmaxf);
            int i0 = (int)p;
            float wv = p - (float)i0;
            int aoo  = (i0 - i0min) * kact;
            if (i==0){w0=wv;o0=1.0f-wv;a0o=aoo;}
            else if (i==1){w1=wv;o1=1.0f-wv;a1o=aoo;}
            else if (i==2){w2=wv;o2=1.0f-wv;a2o=aoo;}
            else {w3=wv;o3=1.0f-wv;a3o=aoo;}
        }
    }
    // wave-wide min for uniform early break
    #pragma unroll
    for (int off = 32; off > 0; off >>= 1)
        um = fminf(um, __shfl_xor(um, off));
    const float umin = um;
    const int lb = (tid & 63) & ~3;            // group base lane within wave

    if (valid) {
        float acc0=0.f, acc1=0.f, acc2=0.f, acc3=0.f;
        const float* s4k = scan4 + (size_t)(b * N + k0) * NG;
        float g0c = (q == 0) ? 0.0f : s4k[q - 1];
        float g1c = s4k[q];

        for (int k = k0; k < kend; ++k) {
            const int   kk = k - k0;
            const float kc = kcs[kk];
            if (kc * umin >= NYQF) break;      // wave-uniform; kc monotone in k
            const float G0 = g0c, G1 = g1c;
            if (k + 1 < kend) {                // prefetch next k row
                const float* nx = s4k + NG;
                g0c = (q == 0) ? 0.0f : nx[q - 1];
                g1c = nx[q];
                s4k = nx;
            }

            // lane-local increments (bit-exact vs ref elementwise ops)
            float x0 = div48000(TWO_PI_F * (kc * u0));
            float x1 = div48000(TWO_PI_F * (kc * u1));
            float x2 = div48000(TWO_PI_F * (kc * u2));
            float x3 = div48000(TWO_PI_F * (kc * u3));
            float L1p = x0 + x1, L1q = x2 + x3;
            float L2  = L1p + L1q;

            // group L2 partials (FP add commutative bitwise -> exact assoc)
            float s0 = __shfl(L2, lb);
            float s1 = __shfl(L2, lb + 1);
            float s2 = __shfl(L2, lb + 2);
            float t01 = s0 + s1;
            float b1v = G0 + s0;               // s20
            float b2v = G0 + t01;              // s3v  (g0 + (L2a+L2b))
            float b3v = b2v + s2;              // s22
            float base = (c == 0) ? G0  : (c == 1) ? b1v : (c == 2) ? b2v : b3v;
            float bn   = (c == 0) ? b1v : (c == 1) ? b2v : (c == 2) ? b3v : G1;

            float ph0 = base + x0;
            float ph1 = base + L1p;
            float ph2 = ph1 + x2;
            float ph3 = bn;

            {   float t1 = kc * u0;            // same RN product as ref mask
                if (t1 < NYQF) { float sv = sin_phase(ph0);
                    float2 a = amps[a0o + kk]; acc0 += (a.x*o0 + a.y*w0) * sv; } }
            {   float t1 = kc * u1;
                if (t1 < NYQF) { float sv = sin_phase(ph1);
                    float2 a = amps[a1o + kk]; acc1 += (a.x*o1 + a.y*w1) * sv; } }
            {   float t1 = kc * u2;
                if (t1 < NYQF) { float sv = sin_phase(ph2);
                    float2 a = amps[a2o + kk]; acc2 += (a.x*o2 + a.y*w2) * sv; } }
            {   float t1 = kc * u3;
                if (t1 < NYQF) { float sv = sin_phase(ph3);
                    float2 a = amps[a3o + kk]; acc3 += (a.x*o3 + a.y*w3) * sv; } }
        }

        const float Nf = (float)N;
        float* ob = out + (size_t)b * n + (size_t)q * 16 + c * 4;
        atomicAdd(&ob[0], acc0 / Nf);
        atomicAdd(&ob[1], acc1 / Nf);
        atomicAdd(&ob[2], acc2 / Nf);
        atomicAdd(&ob[3], acc3 / Nf);
    }
}

// ---- Fallback: round-5 proven kernel (atomics, 96 KB LDS) ------------------
__global__ void __launch_bounds__(256) k_scan_synth(
        const float* __restrict__ harm, const float* __restrict__ f0up,
        const float* __restrict__ inh,  float* __restrict__ out,
        int B, int T, int N, int n, float pf) {
    extern __shared__ float lv[];
    const int k   = blockIdx.x;
    const int b   = blockIdx.y;
    const int tid = threadIdx.x;
    const float kc = kcval(k, inh[b]);
    const float* fb = f0up + (size_t)b * n;

    auto inc = [&](int j) -> float {
        float u    = fb[j];
        float inst = kc * u;
        float tt   = TWO_PI_F * inst;
        return tt / SRF;
    };

    const int len1 = n >> 1;
    {
        const float4* f4 = (const float4*)fb;
        for (int i = tid; i < (n >> 2); i += 256) {
            float4 u = f4[i];
            float a0 = (TWO_PI_F * (kc * u.x)) / SRF;
            float a1 = (TWO_PI_F * (kc * u.y)) / SRF;
            float a2 = (TWO_PI_F * (kc * u.z)) / SRF;
            float a3 = (TWO_PI_F * (kc * u.w)) / SRF;
            lv[i] = (a0 + a1) + (a2 + a3);
        }
    }
    __syncthreads();
    int offp = 0, lenp = n >> 2, P = 2;
    for (int l = 3; ; ++l) {
        int lenc = lenp >> 1;
        int offc = offp + lenp;
        for (int i = tid; i < lenc; i += 256)
            lv[offc + i] = lv[offp + 2*i] + lv[offp + 2*i + 1];
        __syncthreads();
        P = l;
        if (lenc == 1) break;
        offp = offc; lenp = lenc;
    }
    for (int l = P - 1; l >= 2; --l) {
        int lenl = n >> l;
        int offl = 0;
        for (int m = 2; m < l; ++m) offl += (n >> m);
        float*       arr = lv + offl;
        const float* hi  = lv + offl + lenl;
        int lenh = n >> (l + 1);
        for (int i = tid; i < lenh; i += 256) {
            float v = hi[i];
            int e = 2*i + 2;
            if (e < lenl) arr[e] = v + arr[e];
            arr[2*i + 1] = v;
        }
        __syncthreads();
    }
    const float* scan2 = lv;

    const float  tmaxf = (float)(T - 1);
    const float  invN  = 1.0f / (float)N;
    const float* hb    = harm + (size_t)b * T * N + k;
    float*       ob    = out + (size_t)b * n;

    auto emit = [&](int j, float ph) {
        float u    = fb[j];
        float inst = kc * u;
        if (!(inst < NYQF)) return;
        double pr = (double)ph * INV_2PI_D;
        double fr = pr - rint(pr);
        float  sv = hsin_rev((float)fr);
        float pos = ((float)j + 0.5f);
        pos = pos * pf; pos = pos - 0.5f;
        pos = fmaxf(pos, 0.0f); pos = fminf(pos, tmaxf);
        int   i0 = (int)pos;
        int   i1 = min(i0 + 1, T - 1);
        float w  = pos - (float)i0;
        float a  = hb[(size_t)i0 * N] * (1.0f - w) + hb[(size_t)i1 * N] * w;
        atomicAdd(&ob[j], (a * sv) * invN);
    };

    if (tid == 0) emit(0, inc(0));
    for (int tt = tid; tt < len1; tt += 256) {
        float s1;
        if (tt == 0)      s1 = inc(0) + inc(1);
        else if (tt & 1)  s1 = scan2[(tt - 1) >> 1];
        else              s1 = scan2[(tt >> 1) - 1] + (inc(2*tt) + inc(2*tt + 1));
        emit(2*tt + 1, s1);
        int je = 2*tt + 2;
        if (je < n) emit(je, s1 + inc(je));
    }
}

extern "C" void kernel_launch(void* const* d_in, const int* in_sizes, int n_in,
                              void* d_out, int out_size, void* d_ws, size_t ws_size,
                              hipStream_t stream) {
    const int B = in_sizes[2];                 // 16
    const int T = in_sizes[1] / B;             // 250
    const int N = in_sizes[0] / (B * T);       // 100
    const int n = out_size / B;                // 48000
    const float pf = (float)((double)T / (double)n);

    const float* harm = (const float*)d_in[0];
    const float* f0   = (const float*)d_in[1];
    const float* inh  = (const float*)d_in[2];
    float* out  = (float*)d_out;
    float* f0up = (float*)d_ws;                // B*n floats = 3.07 MB

    const int KZ  = 4;
    const int kpg = (N + KZ - 1) / KZ;         // 25
    const size_t needFast = (size_t)B * n * 4 + (size_t)B * N * (n / 16) * 4;
    const bool fast = (ws_size >= needFast) && (n % 16 == 0) && (kpg <= 32);

    k_f0up<<<dim3((n + 255) / 256, B), 256, 0, stream>>>(f0, f0up, out, T, n, pf);

    if (fast) {
        float* scan4 = (float*)((char*)d_ws + (size_t)B * n * 4);
        k_scan4<<<dim3(N, B), 256, 0, stream>>>(f0up, inh, scan4, N, n);
        const int NG    = n / 16;                          // 3000
        const int tiles = (NG * 4 + 255) / 256;            // 47
        k_synth4<<<dim3(tiles, B, KZ), 256, 0, stream>>>(
            harm, f0up, inh, scan4, out, B, T, N, n, pf, kpg);
    } else {
        const size_t lds_bytes = (size_t)(n / 2) * sizeof(float);  // 96 KB
        k_scan_synth<<<dim3(N, B), 256, lds_bytes, stream>>>(
            harm, f0up, inh, out, B, T, N, n, pf);
    }
}

// Round 12
// 153.457 us; speedup vs baseline: 1.9037x; 1.0077x over previous
//
#include <hip/hip_runtime.h>
#include <cmath>

// ---------------------------------------------------------------------------
// Bit-exact replication of the reference's f32 cumsum TREE (JAX associative
// scan), validated rounds 5-11 (absmax 1.831e-3 all — bf16-quantized compare,
// == bf16 ulp at |out|max, so non-chaotic-path deltas <1e-6 are free).
// Round 11 accounting: synth4 64 us (issue-bound: ~115 VALU + 7 LDS-pipe per
// wave-iter), scan4 ~40 us, ~15 us/dispatch fixed. This round shaves the
// synth4 inner loop only: (1) amps staged as (a0, a1-a0) -> blend+acc = 2
// fmaf (non-chaotic path); (2) scan4 rows padded with a leading zero ->
// g0/g1 prefetch without q==0 cndmasks; (3) group broadcasts via ds_swizzle
// immediates instead of dynamic-lane shuffles. Chaotic-path dag unchanged.
// ---------------------------------------------------------------------------
#pragma clang fp contract(off)

#define SRF   48000.0f
#define NYQF  21600.0f                    // fp32(48000*0.45), exact
constexpr float  TWO_PI_F  = 6.283185307179586476925286766559f;  // 0x40C90FDB
constexpr double INV_2PI_D = 0.15915494309189533576888376337251;
constexpr float  RC1 = (float)INV_2PI_D;
constexpr float  RC2 = (float)(INV_2PI_D - (double)RC1);
constexpr double INV_SR_D = 1.0 / 48000.0;
constexpr float  DD1 = (float)INV_SR_D;
constexpr float  DD2 = (float)(INV_SR_D - (double)DD1);

__device__ __forceinline__ float hsin_rev(float r) {  // sin(2*pi*r)
#if __has_builtin(__builtin_amdgcn_sinf)
    return __builtin_amdgcn_sinf(r);                  // v_sin_f32: revolutions
#else
    return __sinf(r * TWO_PI_F);
#endif
}

// Correctly-rounded t/48000 via double-float mul (== IEEE f32 divide here;
// proved: no halfway cases, err 2^-47 << 2^-33.5 boundary distance).
__device__ __forceinline__ float div48000(float t) {
    float h = t * DD1;
    float r = __builtin_fmaf(t, DD1, -h);
    float s = __builtin_fmaf(t, DD2, r);
    return h + s;
}

// sin(ph) for f32 ph: double-float reduction to revolutions (|err|<=2^-25 rev)
__device__ __forceinline__ float sin_phase(float ph) {
    float h  = ph * RC1;
    float r  = __builtin_fmaf(ph, RC1, -h);
    float s  = __builtin_fmaf(ph, RC2, r);
    float nn = __builtin_rintf(h);
    float fr = (h - nn) + s;
    return hsin_rev(fr);
}

// group-of-4 broadcast: value of lane (lane&~3)+idx  (idx=0,1,2 static)
template <int IDX>
__device__ __forceinline__ float grp4_bcast(float v, int lb) {
#if __has_builtin(__builtin_amdgcn_ds_swizzle)
    // BitMode: offset = (xor<<10)|(or<<5)|and ; and=0x1C clears low 2 bits
    constexpr int imm = (IDX << 5) | 0x1C;
    return __int_as_float(__builtin_amdgcn_ds_swizzle(__float_as_int(v), imm));
#else
    return __shfl(v, lb + IDX);
#endif
}

// kc[b,k] = fp32(k * fp32(sqrt(fp32(1 + fp32(inh*k^2)))))  -- np/jnp-exact
__device__ __forceinline__ float kcval(int k, float ib) {
    float kf = (float)(k + 1);
    float k2 = kf * kf;
    float m  = ib * k2;
    float s1 = 1.0f + m;
    float st = (float)sqrt((double)s1);
    return kf * st;
}

// ---- K1: f0_up[b,j] (np-exact fp32 interp) + zero-init of out --------------
__global__ void __launch_bounds__(256) k_f0up(const float* __restrict__ f0,
        float* __restrict__ f0up, float* __restrict__ out,
        int T, int n, float pf) {
    int j = blockIdx.x * 256 + threadIdx.x;
    int b = blockIdx.y;
    if (j >= n) return;
    float pos = ((float)j + 0.5f);
    pos = pos * pf;
    pos = pos - 0.5f;
    pos = fmaxf(pos, 0.0f);
    pos = fminf(pos, (float)(T - 1));
    int   i0 = (int)pos;
    int   i1 = min(i0 + 1, T - 1);
    float w  = pos - (float)i0;
    float omw = 1.0f - w;
    const float* fb = f0 + b * T;
    f0up[(size_t)b * n + j] = fb[i0] * omw + fb[i1] * w;
    out[(size_t)b * n + j]  = 0.0f;            // harness poisons out; we own it
}

// ---- K2a: per (b,k) produce scan4 (level-4 inclusive tree scan) ------------
// Output rows padded: sp[0] = 0, sp[1+i] = scan4[i]  (NG+1 floats per row).
__global__ void __launch_bounds__(256) k_scan4(const float* __restrict__ f0up,
        const float* __restrict__ inh, float* __restrict__ scan4,
        int N, int n) {
    __shared__ float lv[6016];
    const int k   = blockIdx.x;
    const int b   = blockIdx.y;
    const int tid = threadIdx.x;
    const float kc = kcval(k, inh[b]);
    const float4* f4 = (const float4*)(f0up + (size_t)b * n);
    const int len4 = n >> 4;

    auto l2of = [&](float4 v) -> float {
        float a0 = div48000(TWO_PI_F * (kc * v.x));
        float a1 = div48000(TWO_PI_F * (kc * v.y));
        float a2 = div48000(TWO_PI_F * (kc * v.z));
        float a3 = div48000(TWO_PI_F * (kc * v.w));
        return (a0 + a1) + (a2 + a3);
    };
    for (int i = tid; i < len4; i += 256) {
        float s01 = l2of(f4[4*i])     + l2of(f4[4*i + 1]);
        float s23 = l2of(f4[4*i + 2]) + l2of(f4[4*i + 3]);
        lv[i] = s01 + s23;                     // L4[i] = L3[2i]+L3[2i+1]
    }
    __syncthreads();

    // upsweep
    int offp = 0, lenp = len4, P = 4;
    for (int l = 5; ; ++l) {
        int lenc = lenp >> 1;
        int offc = offp + lenp;
        for (int i = tid; i < lenc; i += 256)
            lv[offc + i] = lv[offp + 2*i] + lv[offp + 2*i + 1];
        __syncthreads();
        P = l;
        if (lenc == 1) break;
        offp = offc; lenp = lenc;
    }
    // downsweep (round-5-validated formulas)
    for (int l = P - 1; l >= 4; --l) {
        int lenl = n >> l;
        int offl = 0;
        for (int m = 4; m < l; ++m) offl += (n >> m);
        int offh = offl + lenl;
        int lenh = n >> (l + 1);
        float*       arr = lv + offl;
        const float* hi  = lv + offh;
        for (int i = tid; i < lenh; i += 256) {
            float v = hi[i];
            int e = 2*i + 2;
            if (e < lenl) arr[e] = v + arr[e];
            arr[2*i + 1] = v;
        }
        __syncthreads();
    }
    float* sp = scan4 + (size_t)(b * N + k) * (len4 + 1);
    if (tid == 0) sp[0] = 0.0f;
    for (int i = tid; i < len4; i += 256) sp[1 + i] = lv[i];
}

// ---- K2b: 4 lanes per 16-j group; tree partials via group broadcasts -------
__global__ void __launch_bounds__(256) k_synth4(
        const float* __restrict__ harm, const float* __restrict__ f0up,
        const float* __restrict__ inh,  const float* __restrict__ scan4,
        float* __restrict__ out, int B, int T, int N, int n, float pf, int kpg) {
    const int tid  = threadIdx.x;
    const int b    = blockIdx.y;
    const int k0   = blockIdx.z * kpg;
    const int g    = blockIdx.x * 256 + tid;   // global lane id
    const int q    = g >> 2;                   // 16-sample group
    const int c    = g & 3;                    // quarter within group
    const int NG   = n >> 4;
    const int NGP  = NG + 1;                   // padded row length
    const int kend = min(k0 + kpg, N);
    const int kact = kend - k0;
    const bool valid = q < NG;

    __shared__ float2 amps[8 * 32];            // (a0, a1-a0) x k (span 1024 j)
    __shared__ float  kcs[32];

    const float ib    = inh[b];
    const float tmaxf = (float)(T - 1);
    for (int i = tid; i < kact; i += 256) kcs[i] = kcval(k0 + i, ib);

    const int j0blk = blockIdx.x * 1024;
    int i0min;
    {
        float p = ((float)j0blk + 0.5f);
        p = p * pf; p = p - 0.5f;
        p = fmaxf(p, 0.0f); p = fminf(p, tmaxf);
        i0min = (int)p;
    }
    for (int idx = tid; idx < 8 * kact; idx += 256) {
        int r = idx / kact, kk = idx - r * kact;
        int r0 = min(i0min + r, T - 1);
        int r1 = min(i0min + r + 1, T - 1);
        float a0 = harm[((size_t)b * T + r0) * N + (k0 + kk)];
        float a1 = harm[((size_t)b * T + r1) * N + (k0 + kk)];
        amps[idx] = make_float2(a0, a1 - a0);  // blend = fmaf(w, d, a0)
    }
    __syncthreads();                           // last barrier

    float u0=0.f,u1=0.f,u2=0.f,u3=0.f;
    float w0=0.f,w1=0.f,w2=0.f,w3=0.f;
    int   a0o=0,a1o=0,a2o=0,a3o=0;
    float um = __builtin_inff();
    if (valid) {
        const float4 v = *(const float4*)(f0up + (size_t)b * n + (size_t)q * 16 + c * 4);
        u0=v.x; u1=v.y; u2=v.z; u3=v.w;
        um = fminf(fminf(u0,u1), fminf(u2,u3));
        const int jb = q * 16 + c * 4;
        #pragma unroll
        for (int i = 0; i < 4; ++i) {
            float p = ((float)(jb + i) + 0.5f);
            p = p * pf; p = p - 0.5f;
            p = fmaxf(p, 0.0f); p = fminf(p, tmaxf);
            int i0 = (int)p;
            float wv = p - (float)i0;
            int aoo  = (i0 - i0min) * kact;
            if (i==0){w0=wv;a0o=aoo;}
            else if (i==1){w1=wv;a1o=aoo;}
            else if (i==2){w2=wv;a2o=aoo;}
            else {w3=wv;a3o=aoo;}
        }
    }
    // wave-wide min for uniform early break
    #pragma unroll
    for (int off = 32; off > 0; off >>= 1)
        um = fminf(um, __shfl_xor(um, off));
    const float umin = um;
    const int lb = (tid & 63) & ~3;            // group base lane (fallback path)

    if (valid) {
        float acc0=0.f, acc1=0.f, acc2=0.f, acc3=0.f;
        const float* s4k = scan4 + (size_t)(b * N + k0) * NGP;
        float g0c = s4k[q];                    // padded row: [0]=0
        float g1c = s4k[q + 1];

        for (int k = k0; k < kend; ++k) {
            const int   kk = k - k0;
            const float kc = kcs[kk];
            if (kc * umin >= NYQF) break;      // wave-uniform; kc monotone in k
            const float G0 = g0c, G1 = g1c;
            if (k + 1 < kend) {                // prefetch next k row
                const float* nx = s4k + NGP;
                g0c = nx[q];
                g1c = nx[q + 1];
                s4k = nx;
            }

            // lane-local increments (bit-exact vs ref elementwise ops)
            float x0 = div48000(TWO_PI_F * (kc * u0));
            float x1 = div48000(TWO_PI_F * (kc * u1));
            float x2 = div48000(TWO_PI_F * (kc * u2));
            float x3 = div48000(TWO_PI_F * (kc * u3));
            float L1p = x0 + x1, L1q = x2 + x3;
            float L2  = L1p + L1q;

            // group L2 partials (FP add commutative bitwise -> exact assoc)
            float s0 = grp4_bcast<0>(L2, lb);
            float s1 = grp4_bcast<1>(L2, lb);
            float s2 = grp4_bcast<2>(L2, lb);
            float t01 = s0 + s1;
            float b1v = G0 + s0;               // s20
            float b2v = G0 + t01;              // s3v  (g0 + (L2a+L2b))
            float b3v = b2v + s2;              // s22
            float base = (c == 0) ? G0  : (c == 1) ? b1v : (c == 2) ? b2v : b3v;
            float bn   = (c == 0) ? b1v : (c == 1) ? b2v : (c == 2) ? b3v : G1;

            float ph0 = base + x0;
            float ph1 = base + L1p;
            float ph2 = ph1 + x2;
            float ph3 = bn;

            {   float t1 = kc * u0;            // same RN product as ref mask
                if (t1 < NYQF) { float sv = sin_phase(ph0);
                    float2 a = amps[a0o + kk];
                    acc0 = __builtin_fmaf(__builtin_fmaf(w0, a.y, a.x), sv, acc0); } }
            {   float t1 = kc * u1;
                if (t1 < NYQF) { float sv = sin_phase(ph1);
                    float2 a = amps[a1o + kk];
                    acc1 = __builtin_fmaf(__builtin_fmaf(w1, a.y, a.x), sv, acc1); } }
            {   float t1 = kc * u2;
                if (t1 < NYQF) { float sv = sin_phase(ph2);
                    float2 a = amps[a2o + kk];
                    acc2 = __builtin_fmaf(__builtin_fmaf(w2, a.y, a.x), sv, acc2); } }
            {   float t1 = kc * u3;
                if (t1 < NYQF) { float sv = sin_phase(ph3);
                    float2 a = amps[a3o + kk];
                    acc3 = __builtin_fmaf(__builtin_fmaf(w3, a.y, a.x), sv, acc3); } }
        }

        const float Nf = (float)N;
        float* ob = out + (size_t)b * n + (size_t)q * 16 + c * 4;
        atomicAdd(&ob[0], acc0 / Nf);
        atomicAdd(&ob[1], acc1 / Nf);
        atomicAdd(&ob[2], acc2 / Nf);
        atomicAdd(&ob[3], acc3 / Nf);
    }
}

// ---- Fallback: round-5 proven kernel (atomics, 96 KB LDS) ------------------
__global__ void __launch_bounds__(256) k_scan_synth(
        const float* __restrict__ harm, const float* __restrict__ f0up,
        const float* __restrict__ inh,  float* __restrict__ out,
        int B, int T, int N, int n, float pf) {
    extern __shared__ float lv[];
    const int k   = blockIdx.x;
    const int b   = blockIdx.y;
    const int tid = threadIdx.x;
    const float kc = kcval(k, inh[b]);
    const float* fb = f0up + (size_t)b * n;

    auto inc = [&](int j) -> float {
        float u    = fb[j];
        float inst = kc * u;
        float tt   = TWO_PI_F * inst;
        return tt / SRF;
    };

    const int len1 = n >> 1;
    {
        const float4* f4 = (const float4*)fb;
        for (int i = tid; i < (n >> 2); i += 256) {
            float4 u = f4[i];
            float a0 = (TWO_PI_F * (kc * u.x)) / SRF;
            float a1 = (TWO_PI_F * (kc * u.y)) / SRF;
            float a2 = (TWO_PI_F * (kc * u.z)) / SRF;
            float a3 = (TWO_PI_F * (kc * u.w)) / SRF;
            lv[i] = (a0 + a1) + (a2 + a3);
        }
    }
    __syncthreads();
    int offp = 0, lenp = n >> 2, P = 2;
    for (int l = 3; ; ++l) {
        int lenc = lenp >> 1;
        int offc = offp + lenp;
        for (int i = tid; i < lenc; i += 256)
            lv[offc + i] = lv[offp + 2*i] + lv[offp + 2*i + 1];
        __syncthreads();
        P = l;
        if (lenc == 1) break;
        offp = offc; lenp = lenc;
    }
    for (int l = P - 1; l >= 2; --l) {
        int lenl = n >> l;
        int offl = 0;
        for (int m = 2; m < l; ++m) offl += (n >> m);
        float*       arr = lv + offl;
        const float* hi  = lv + offl + lenl;
        int lenh = n >> (l + 1);
        for (int i = tid; i < lenh; i += 256) {
            float v = hi[i];
            int e = 2*i + 2;
            if (e < lenl) arr[e] = v + arr[e];
            arr[2*i + 1] = v;
        }
        __syncthreads();
    }
    const float* scan2 = lv;

    const float  tmaxf = (float)(T - 1);
    const float  invN  = 1.0f / (float)N;
    const float* hb    = harm + (size_t)b * T * N + k;
    float*       ob    = out + (size_t)b * n;

    auto emit = [&](int j, float ph) {
        float u    = fb[j];
        float inst = kc * u;
        if (!(inst < NYQF)) return;
        double pr = (double)ph * INV_2PI_D;
        double fr = pr - rint(pr);
        float  sv = hsin_rev((float)fr);
        float pos = ((float)j + 0.5f);
        pos = pos * pf; pos = pos - 0.5f;
        pos = fmaxf(pos, 0.0f); pos = fminf(pos, tmaxf);
        int   i0 = (int)pos;
        int   i1 = min(i0 + 1, T - 1);
        float w  = pos - (float)i0;
        float a  = hb[(size_t)i0 * N] * (1.0f - w) + hb[(size_t)i1 * N] * w;
        atomicAdd(&ob[j], (a * sv) * invN);
    };

    if (tid == 0) emit(0, inc(0));
    for (int tt = tid; tt < len1; tt += 256) {
        float s1;
        if (tt == 0)      s1 = inc(0) + inc(1);
        else if (tt & 1)  s1 = scan2[(tt - 1) >> 1];
        else              s1 = scan2[(tt >> 1) - 1] + (inc(2*tt) + inc(2*tt + 1));
        emit(2*tt + 1, s1);
        int je = 2*tt + 2;
        if (je < n) emit(je, s1 + inc(je));
    }
}

extern "C" void kernel_launch(void* const* d_in, const int* in_sizes, int n_in,
                              void* d_out, int out_size, void* d_ws, size_t ws_size,
                              hipStream_t stream) {
    const int B = in_sizes[2];                 // 16
    const int T = in_sizes[1] / B;             // 250
    const int N = in_sizes[0] / (B * T);       // 100
    const int n = out_size / B;                // 48000
    const float pf = (float)((double)T / (double)n);

    const float* harm = (const float*)d_in[0];
    const float* f0   = (const float*)d_in[1];
    const float* inh  = (const float*)d_in[2];
    float* out  = (float*)d_out;
    float* f0up = (float*)d_ws;                // B*n floats = 3.07 MB

    const int KZ  = 4;
    const int kpg = (N + KZ - 1) / KZ;         // 25
    const int NG  = n / 16;                    // 3000
    const size_t needFast = (size_t)B * n * 4 + (size_t)B * N * (NG + 1) * 4;
    const bool fast = (ws_size >= needFast) && (n % 16 == 0) && (kpg <= 32);

    k_f0up<<<dim3((n + 255) / 256, B), 256, 0, stream>>>(f0, f0up, out, T, n, pf);

    if (fast) {
        float* scan4 = (float*)((char*)d_ws + (size_t)B * n * 4);
        k_scan4<<<dim3(N, B), 256, 0, stream>>>(f0up, inh, scan4, N, n);
        const int tiles = (NG * 4 + 255) / 256;            // 47
        k_synth4<<<dim3(tiles, B, KZ), 256, 0, stream>>>(
            harm, f0up, inh, scan4, out, B, T, N, n, pf, kpg);
    } else {
        const size_t lds_bytes = (size_t)(n / 2) * sizeof(float);  // 96 KB
        k_scan_synth<<<dim3(N, B), 256, lds_bytes, stream>>>(
            harm, f0up, inh, out, B, T, N, n, pf);
    }
}